// Round 10
// baseline (1005.677 us; speedup 1.0000x reference)
//
#include <hip/hip_runtime.h>

// Problem constants (fixed by reference)
#define NE 8
#define TT 2048            // tokens per expert
#define KD 2048            // INPUT_SIZE  (K)
#define ND 8192            // OUTPUT_SIZE (N)
#define MT (NE * TT)       // 16384 total rows
#define NW ((size_t)NE * ND * KD)   // 134217728 weight elems
#define NX ((size_t)MT * KD)        // 33554432 input elems

typedef _Float16 f16;
typedef _Float16 f16x4 __attribute__((ext_vector_type(4)));
typedef _Float16 f16x8 __attribute__((ext_vector_type(8)));
typedef float    f32x4 __attribute__((ext_vector_type(4)));

// ---------------- K1: partial abs-sum (f64, deterministic) ----------------
__global__ void k_abs_partial(const float* __restrict__ w, double* __restrict__ part) {
    __shared__ double sred[256];
    const size_t n4 = NW / 4;
    const size_t stride = (size_t)gridDim.x * blockDim.x;
    double acc = 0.0;
    for (size_t i = (size_t)blockIdx.x * blockDim.x + threadIdx.x; i < n4; i += stride) {
        float4 v = ((const float4*)w)[i];
        acc += (double)fabsf(v.x) + (double)fabsf(v.y) + (double)fabsf(v.z) + (double)fabsf(v.w);
    }
    sred[threadIdx.x] = acc;
    __syncthreads();
    for (int s = 128; s > 0; s >>= 1) {
        if ((int)threadIdx.x < s) sred[threadIdx.x] += sred[threadIdx.x + s];
        __syncthreads();
    }
    if (threadIdx.x == 0) part[blockIdx.x] = sred[0];
}

// ---------------- K2: finalize scale ----------------
__global__ void k_finalize(const double* __restrict__ part, double* __restrict__ sc) {
    __shared__ double sred[256];
    double a = 0.0;
    for (int i = threadIdx.x; i < 2048; i += 256) a += part[i];
    sred[threadIdx.x] = a;
    __syncthreads();
    for (int s = 128; s > 0; s >>= 1) {
        if ((int)threadIdx.x < s) sred[threadIdx.x] += sred[threadIdx.x + s];
        __syncthreads();
    }
    if (threadIdx.x == 0) {
        double mean = sred[0] / (double)NW;
        double denom = mean > 1e-5 ? mean : 1e-5;
        sc[0] = 1.0 / denom;   // scale
        sc[1] = denom;         // 1/scale (output multiplier)
    }
}

// ---------------- K3: quantize w -> ternary f16 ----------------
__global__ void k_quant(const float* __restrict__ w, const double* __restrict__ sc,
                        f16* __restrict__ q) {
    const double scale = sc[0];
    const size_t n4 = NW / 4;
    const size_t stride = (size_t)gridDim.x * blockDim.x;
    for (size_t i = (size_t)blockIdx.x * blockDim.x + threadIdx.x; i < n4; i += stride) {
        float4 v = ((const float4*)w)[i];
        f16x4 o;
        o[0] = (f16)(float)fmin(fmax(rint((double)v.x * scale), -1.0), 1.0);
        o[1] = (f16)(float)fmin(fmax(rint((double)v.y * scale), -1.0), 1.0);
        o[2] = (f16)(float)fmin(fmax(rint((double)v.z * scale), -1.0), 1.0);
        o[3] = (f16)(float)fmin(fmax(rint((double)v.w * scale), -1.0), 1.0);
        ((f16x4*)q)[i] = o;
    }
}

// ---------------- K4: x f32 -> f16 ----------------
__global__ void k_xconv(const float* __restrict__ x, f16* __restrict__ xh) {
    const size_t n4 = NX / 4;
    const size_t stride = (size_t)gridDim.x * blockDim.x;
    for (size_t i = (size_t)blockIdx.x * blockDim.x + threadIdx.x; i < n4; i += stride) {
        float4 v = ((const float4*)x)[i];
        f16x4 o;
        o[0] = (f16)v.x; o[1] = (f16)v.y; o[2] = (f16)v.z; o[3] = (f16)v.w;
        ((f16x4*)xh)[i] = o;
    }
}

// ---------------- K5: grouped GEMM, 256x256x64, FAT WAVES ------------------
// 4 waves (1 per SIMD, <=512 VGPR), per-wave output 128x128 (acc 8x8 f32x4 =
// 256 VGPR). LDS: 2 bufs x [A 32K | B 32K] = 128 KiB; region = 256 rows x
// 128 B (BK=64 contiguous per row).
// NEW swizzle (conflict-free for 8-lane b128 groups): 8 slots of 16 B/row,
//   phys_slot = slot ^ (row & 7).
// Reads: lanes li=0..15 read rows base+li, slot kh*4+sl -> phys = slot^(li&7)
//   (16-aligned base): any 8 consecutive lanes hit 8 distinct bank-quads.
// Staging: gload writes 1 KiB linear = 8 full rows; inverse swizzle on the
//   per-lane GLOBAL source: lane l -> row +(l>>3), slot (l&7)^(l>>3).
// Per K-tile body (all waits provably ~free):
//   lgkm0 | issue 16 ds_read kh1(t) | barrier | stage(t+1) 16 gloads |
//   64 MFMA kh0 | lgkm0 | vmcnt(0) (issued ~1242cy earlier) | barrier |
//   issue 16 ds_read kh0(t+1) (read-ahead) | 64 MFMA kh1
// gload imm stays 0 ALWAYS (nonzero shifts global AND LDS: round-4 NaN).

__device__ __forceinline__ void gload16(const void* g, void* l) {
    __builtin_amdgcn_global_load_lds(
        (const __attribute__((address_space(1))) unsigned int*)g,
        (__attribute__((address_space(3))) unsigned int*)l, 16, 0, 0);
}

#define BARR() asm volatile("s_barrier" ::: "memory")
#define SCHED0() __builtin_amdgcn_sched_barrier(0)
#define LGKM0() do { asm volatile("s_waitcnt lgkmcnt(0)" ::: "memory"); SCHED0(); } while (0)
#define VM0() asm volatile("s_waitcnt vmcnt(0)" ::: "memory")

// 16 fragment reads for one k-half: 8 A + 8 B (base VGPR + imm m*2048 <= 14336)
#define RD16(AP, BP, FA, FB) do { \
  _Pragma("unroll") for (int m_ = 0; m_ < 8; ++m_) \
    FA[m_] = *(const f16x8*)((AP) + m_ * 2048); \
  _Pragma("unroll") for (int n_ = 0; n_ < 8; ++n_) \
    FB[n_] = *(const f16x8*)((BP) + n_ * 2048); \
} while (0)

// 64 MFMA, all-independent accumulators
#define MM64(FA, FB) do { \
  _Pragma("unroll") for (int m_ = 0; m_ < 8; ++m_) \
    _Pragma("unroll") for (int n_ = 0; n_ < 8; ++n_) \
      acc[m_][n_] = __builtin_amdgcn_mfma_f32_16x16x32_f16( \
          FA[m_], FB[n_], acc[m_][n_], 0, 0, 0); \
} while (0)

// stage one full tile (A 32K + B 32K) into buffer at byte SB; 16 gloads/wave
#define STG16(SB) do { \
  _Pragma("unroll") for (int j_ = 0; j_ < 8; ++j_) \
    gload16(pA + j_ * 32768, dstA + (SB) + j_ * 1024); \
  _Pragma("unroll") for (int j_ = 0; j_ < 8; ++j_) \
    gload16(pB + j_ * 32768, dstA + (SB) + 32768 + j_ * 1024); \
  pA += 128; pB += 128; \
  asm volatile("" : "+v"(pA), "+v"(pB)); \
} while (0)

// body t: cur buffer (CK1A/CK1B = kh1 read ptrs), stage -> SB, read-ahead
// kh0(t+1) from (NK0A/NK0B)
#define BODY(CK1A, CK1B, SB, NK0A, NK0B) do { \
    LGKM0(); \
    RD16(CK1A, CK1B, fa1, fb1); SCHED0(); \
    BARR(); \
    STG16(SB); \
    MM64(fa0, fb0); \
    LGKM0(); \
    VM0(); BARR(); \
    RD16(NK0A, NK0B, fa0, fb0); SCHED0(); \
    MM64(fa1, fb1); \
} while (0)

__global__ __launch_bounds__(256, 1)
void k_gemm(const f16* __restrict__ xh, const f16* __restrict__ qh,
            const double* __restrict__ sc, float* __restrict__ out) {
    __shared__ char lds[2 * 65536];

    const int lane = (int)threadIdx.x & 63;
    const int wid  = (int)threadIdx.x >> 6;   // 0..3
    const int wr   = wid >> 1;                 // 0..1 (M strip of 128)
    const int wc   = wid & 1;                  // 0..1 (N strip of 128)
    const int li   = lane & 15;
    const int sl   = lane >> 4;                // k-slot 0..3 within a k-half

    // XCD-aware swizzle + round-6 block mapping (FETCH ~0.4 GB proven)
    const int wg = ((int)blockIdx.x & 7) * 256 + ((int)blockIdx.x >> 3);
    const int e  = wg >> 8;
    const int u  = wg & 255;
    const int mt = (u >> 1) & 7;
    const int nt = (((u >> 4) << 1) | (u & 1));

    const f16* Ab = xh + ((size_t)e * TT + (size_t)mt * 256) * KD;
    const f16* Bb = qh + ((size_t)e * ND + (size_t)nt * 256) * KD;
    float*     Cb = out + ((size_t)e * TT + (size_t)mt * 256) * ND + (size_t)nt * 256;

    const float sfac = (float)sc[1];
    asm volatile("s_waitcnt vmcnt(0)" ::: "memory");

    // read pointers: phys_slot = slot ^ (li&7); slot = kh*4 + sl
    const int l7 = li & 7;
    const char* aK0B0 = (const char*)lds +
        ((wr * 128 + li) << 7) + ((sl ^ l7) << 4);
    const char* aK1B0 = (const char*)lds +
        ((wr * 128 + li) << 7) + (((4 + sl) ^ l7) << 4);
    const char* bK0B0 = (const char*)lds + 32768 +
        ((wc * 128 + li) << 7) + ((sl ^ l7) << 4);
    const char* bK1B0 = (const char*)lds + 32768 +
        ((wc * 128 + li) << 7) + (((4 + sl) ^ l7) << 4);
    const char* aK0B1 = aK0B0 + 65536;
    const char* aK1B1 = aK1B0 + 65536;
    const char* bK0B1 = bK0B0 + 65536;
    const char* bK1B1 = bK1B0 + 65536;

    // staging: wave owns rows wid*64..+63 (8 chunks of 8 rows each);
    // lane l: row +(l>>3), global slot = (l&7) ^ (l>>3)  (inverse swizzle)
    const int gslot = (lane & 7) ^ (lane >> 3);
    char* dstA = (char*)lds + wid * 8192;
    const char* pA = (const char*)(Ab + ((size_t)(wid * 64 + (lane >> 3))) * KD + gslot * 8);
    const char* pB = (const char*)(Bb + ((size_t)(wid * 64 + (lane >> 3))) * KD + gslot * 8);

    f32x4 acc[8][8];
#pragma unroll
    for (int m = 0; m < 8; ++m)
#pragma unroll
        for (int n = 0; n < 8; ++n) acc[m][n] = (f32x4){0.f, 0.f, 0.f, 0.f};

    f16x8 fa0[8], fb0[8], fa1[8], fb1[8];

    // prologue: stage tile 0 -> buf0; read kh0(0)
    STG16(0);
    VM0(); BARR();
    RD16(aK0B0, bK0B0, fa0, fb0); SCHED0();

    // bodies t = 0..29 (pairs), 30, then tail 31
#pragma unroll 1
    for (int j = 0; j < 15; ++j) {
        BODY(aK1B0, bK1B0, 65536, aK0B1, bK0B1);   // even t: cur buf0, stage buf1
        BODY(aK1B1, bK1B1, 0,     aK0B0, bK0B0);   // odd t:  cur buf1, stage buf0
    }
    BODY(aK1B0, bK1B0, 65536, aK0B1, bK0B1);       // t=30 (stages tile 31)
    // t=31 tail (cur buf1, no stage)
    LGKM0();
    RD16(aK1B1, bK1B1, fa1, fb1); SCHED0();
    MM64(fa0, fb0);
    LGKM0();
    MM64(fa1, fb1);

    // ---- epilogue: scale by 1/scale, f32 store (verified 16x16 layout) ----
#pragma unroll
    for (int m = 0; m < 8; ++m)
#pragma unroll
        for (int n = 0; n < 8; ++n)
#pragma unroll
            for (int r4 = 0; r4 < 4; ++r4) {
                const int row = wr * 128 + m * 16 + sl * 4 + r4;
                const int col = wc * 128 + n * 16 + li;
                Cb[(size_t)row * ND + col] = acc[m][n][r4] * sfac;
            }
}

// ---------------- fallback (only if ws too small): f32 tiled, on-the-fly quant ----------------
__global__ void k_fallback(const float* __restrict__ x, const float* __restrict__ w,
                           const double* __restrict__ sc, float* __restrict__ out) {
    const int row0 = blockIdx.x * 16;
    const int col0 = blockIdx.y * 16;
    const int e = row0 / TT;
    __shared__ float xs[16][17];
    __shared__ float wq[16][17];
    const double scale = sc[0];
    const float s = (float)sc[1];
    const int tx = threadIdx.x, ty = threadIdx.y;
    const float* wbase = w + ((size_t)e * ND + col0) * KD;
    float acc = 0.f;
    for (int k0 = 0; k0 < KD; k0 += 16) {
        xs[ty][tx] = x[(size_t)(row0 + ty) * KD + k0 + tx];
        const float wv = wbase[(size_t)ty * KD + k0 + tx];
        wq[ty][tx] = (float)fmin(fmax(rint((double)wv * scale), -1.0), 1.0);
        __syncthreads();
#pragma unroll
        for (int kk = 0; kk < 16; ++kk) acc += xs[ty][kk] * wq[tx][kk];
        __syncthreads();
    }
    out[(size_t)(row0 + ty) * ND + col0 + tx] = acc * s;
}

// ---------------- launch ----------------
extern "C" void kernel_launch(void* const* d_in, const int* in_sizes, int n_in,
                              void* d_out, int out_size, void* d_ws, size_t ws_size,
                              hipStream_t stream) {
    const float* x = (const float*)d_in[0];
    const float* w = (const float*)d_in[1];
    float* out = (float*)d_out;

    double* part = (double*)d_ws;                       // 2048 * 8 B
    double* sc   = (double*)((char*)d_ws + 16384);      // [0]=scale, [1]=1/scale

    const size_t need = 65536 + NX * 2 + NW * 2;        // ~320 MiB

    hipLaunchKernelGGL(k_abs_partial, dim3(2048), dim3(256), 0, stream, w, part);
    hipLaunchKernelGGL(k_finalize,   dim3(1),    dim3(256), 0, stream, part, sc);

    if (ws_size >= need) {
        f16* xh = (f16*)((char*)d_ws + 65536);
        f16* qh = (f16*)((char*)d_ws + 65536 + NX * 2);
        hipLaunchKernelGGL(k_quant, dim3(2048), dim3(256), 0, stream, w, sc, qh);
        hipLaunchKernelGGL(k_xconv, dim3(2048), dim3(256), 0, stream, x, xh);
        hipLaunchKernelGGL(k_gemm,  dim3(NE * (TT / 256) * (ND / 256)), dim3(256), 0, stream,
                           xh, qh, sc, out);
    } else {
        dim3 grid(MT / 16, ND / 16);
        hipLaunchKernelGGL(k_fallback, grid, dim3(16, 16), 0, stream, x, w, sc, out);
    }
}

// Round 11
// 988.871 us; speedup vs baseline: 1.0170x; 1.0170x over previous
//
#include <hip/hip_runtime.h>

// Problem constants (fixed by reference)
#define NE 8
#define TT 2048            // tokens per expert
#define KD 2048            // INPUT_SIZE  (K)
#define ND 8192            // OUTPUT_SIZE (N)
#define MT (NE * TT)       // 16384 total rows
#define NW ((size_t)NE * ND * KD)   // 134217728 weight elems
#define NX ((size_t)MT * KD)        // 33554432 input elems

typedef _Float16 f16;
typedef _Float16 f16x4 __attribute__((ext_vector_type(4)));
typedef _Float16 f16x8 __attribute__((ext_vector_type(8)));
typedef float    f32x4 __attribute__((ext_vector_type(4)));

// ---------------- K1: partial abs-sum (f64, deterministic) ----------------
__global__ void k_abs_partial(const float* __restrict__ w, double* __restrict__ part) {
    __shared__ double sred[256];
    const size_t n4 = NW / 4;
    const size_t stride = (size_t)gridDim.x * blockDim.x;
    double acc = 0.0;
    for (size_t i = (size_t)blockIdx.x * blockDim.x + threadIdx.x; i < n4; i += stride) {
        float4 v = ((const float4*)w)[i];
        acc += (double)fabsf(v.x) + (double)fabsf(v.y) + (double)fabsf(v.z) + (double)fabsf(v.w);
    }
    sred[threadIdx.x] = acc;
    __syncthreads();
    for (int s = 128; s > 0; s >>= 1) {
        if ((int)threadIdx.x < s) sred[threadIdx.x] += sred[threadIdx.x + s];
        __syncthreads();
    }
    if (threadIdx.x == 0) part[blockIdx.x] = sred[0];
}

// ---------------- K2: finalize scale ----------------
__global__ void k_finalize(const double* __restrict__ part, double* __restrict__ sc) {
    __shared__ double sred[256];
    double a = 0.0;
    for (int i = threadIdx.x; i < 2048; i += 256) a += part[i];
    sred[threadIdx.x] = a;
    __syncthreads();
    for (int s = 128; s > 0; s >>= 1) {
        if ((int)threadIdx.x < s) sred[threadIdx.x] += sred[threadIdx.x + s];
        __syncthreads();
    }
    if (threadIdx.x == 0) {
        double mean = sred[0] / (double)NW;
        double denom = mean > 1e-5 ? mean : 1e-5;
        sc[0] = 1.0 / denom;   // scale
        sc[1] = denom;         // 1/scale (output multiplier)
    }
}

// ---------------- K3: quantize w -> ternary f16 ----------------
__global__ void k_quant(const float* __restrict__ w, const double* __restrict__ sc,
                        f16* __restrict__ q) {
    const double scale = sc[0];
    const size_t n4 = NW / 4;
    const size_t stride = (size_t)gridDim.x * blockDim.x;
    for (size_t i = (size_t)blockIdx.x * blockDim.x + threadIdx.x; i < n4; i += stride) {
        float4 v = ((const float4*)w)[i];
        f16x4 o;
        o[0] = (f16)(float)fmin(fmax(rint((double)v.x * scale), -1.0), 1.0);
        o[1] = (f16)(float)fmin(fmax(rint((double)v.y * scale), -1.0), 1.0);
        o[2] = (f16)(float)fmin(fmax(rint((double)v.z * scale), -1.0), 1.0);
        o[3] = (f16)(float)fmin(fmax(rint((double)v.w * scale), -1.0), 1.0);
        ((f16x4*)q)[i] = o;
    }
}

// ---------------- K4: x f32 -> f16 ----------------
__global__ void k_xconv(const float* __restrict__ x, f16* __restrict__ xh) {
    const size_t n4 = NX / 4;
    const size_t stride = (size_t)gridDim.x * blockDim.x;
    for (size_t i = (size_t)blockIdx.x * blockDim.x + threadIdx.x; i < n4; i += stride) {
        float4 v = ((const float4*)x)[i];
        f16x4 o;
        o[0] = (f16)v.x; o[1] = (f16)v.y; o[2] = (f16)v.z; o[3] = (f16)v.w;
        ((f16x4*)xh)[i] = o;
    }
}

// ---------------- K5: grouped GEMM, 256x128x32, TWO BLOCKS PER CU ----------
// The round-11 bet: per-CU overlap comes from 2 INDEPENDENT blocks (separate
// barriers), not from intra-block scheduling (rounds 2-10: one resident block
// -> LDS window and MFMA window strictly ADD -> MfmaUtil stuck at ~39%).
// Block: 256(M) x 128(N), 4 waves (2x2), wave-tile 128x64, BK=32.
// LDS: 2 bufs x [A 16K | B 8K] = 48 KiB  -> 2 blocks/CU (LDS-wise 3, regs 2).
// __launch_bounds__(256,2): <=256 VGPR/wave, 2 waves/SIMD = one per block.
// Per K-tile body (classic dbuf, ONE barrier):
//   STG6 (6 gloads -> other buf) | RD12 (12 ds_read_b128, cur buf) | lgkm0 |
//   32 MFMA (setprio) | vm0 | s_barrier
// vm0's exposure (L2/L3 latency minus RD12+MM32) is covered by the OTHER
// block resident on the same SIMDs.
// Swizzle/staging pair and C layout are the round-3/6/8 verified ones.
// gload imm stays 0 ALWAYS (nonzero shifts global AND LDS: round-4 NaN).
#define NTK 64   // KD / 32

__device__ __forceinline__ void gload16(const void* g, void* l) {
    __builtin_amdgcn_global_load_lds(
        (const __attribute__((address_space(1))) unsigned int*)g,
        (__attribute__((address_space(3))) unsigned int*)l, 16, 0, 0);
}

#define BARR() asm volatile("s_barrier" ::: "memory")
#define SCHED0() __builtin_amdgcn_sched_barrier(0)
#define LGKM0() do { asm volatile("s_waitcnt lgkmcnt(0)" ::: "memory"); SCHED0(); } while (0)
#define VM0() asm volatile("s_waitcnt vmcnt(0)" ::: "memory")

// stage one 24-KiB tile into buffer at byte SB: A 4 chunks + B 2 chunks /wave
#define STG6(SB) do { \
    gload16(pA0, dA + (SB)); \
    gload16(pA1, dA + (SB) + 1024); \
    gload16(pA2, dA + (SB) + 2048); \
    gload16(pA3, dA + (SB) + 3072); \
    gload16(pB0, dB + (SB)); \
    gload16(pB1, dB + (SB) + 1024); \
    pA0 += 64; pA1 += 64; pA2 += 64; pA3 += 64; pB0 += 64; pB1 += 64; \
    asm volatile("" : "+v"(pA0), "+v"(pA1), "+v"(pA2), "+v"(pA3), \
                      "+v"(pB0), "+v"(pB1)); \
} while (0)

// 12 fragment reads: base VGPR + compile-time imm
#define RD12(AR, BR) do { \
  _Pragma("unroll") for (int m_ = 0; m_ < 8; ++m_) \
    af[m_] = *(const f16x8*)((AR) + m_ * 1024); \
  _Pragma("unroll") for (int n_ = 0; n_ < 4; ++n_) \
    bf[n_] = *(const f16x8*)((BR) + n_ * 1024); \
} while (0)

#define MM32() do { \
  __builtin_amdgcn_s_setprio(1); \
  _Pragma("unroll") for (int m_ = 0; m_ < 8; ++m_) \
    _Pragma("unroll") for (int n_ = 0; n_ < 4; ++n_) \
      acc[m_][n_] = __builtin_amdgcn_mfma_f32_16x16x32_f16( \
          af[m_], bf[n_], acc[m_][n_], 0, 0, 0); \
  __builtin_amdgcn_s_setprio(0); } while (0)

#define BODY(AR, BR, SB) do { \
    STG6(SB); \
    RD12(AR, BR); \
    LGKM0(); \
    MM32(); \
    VM0(); BARR(); \
} while (0)

__global__ __launch_bounds__(256, 2)
void k_gemm(const f16* __restrict__ xh, const f16* __restrict__ qh,
            const double* __restrict__ sc, float* __restrict__ out) {
    __shared__ char lds[49152];   // 2 x [A 16K | B 8K]

    const int lane = (int)threadIdx.x & 63;
    const int wid  = (int)threadIdx.x >> 6;   // 0..3
    const int wr   = wid >> 1;                 // 0..1 (M strip of 128)
    const int wc   = wid & 1;                  // 0..1 (N strip of 64)
    const int li   = lane & 15;
    const int sl   = lane >> 4;                // k-slot 0..3

    // XCD-aware swizzle; 4096 wgs, 512 per XCD (one expert each).
    // u bits: [b0 nt_off][b1-b3 mt][b4-b8 nt_blk] -> 2-wide nt windows with
    // fast mt cycling (round-6 mapping family; FETCH ~compulsory proven).
    const int wg = ((int)blockIdx.x & 7) * 512 + ((int)blockIdx.x >> 3);
    const int e  = wg >> 9;
    const int u  = wg & 511;
    const int mt = (u >> 1) & 7;                   // 0..7   (M/256)
    const int nt = ((u >> 4) << 1) | (u & 1);      // 0..63  (N/128)

    const f16* Ab = xh + ((size_t)e * TT + (size_t)mt * 256) * KD;
    const f16* Bb = qh + ((size_t)e * ND + (size_t)nt * 128) * KD;
    float*     Cb = out + ((size_t)e * TT + (size_t)mt * 256) * ND + (size_t)nt * 128;

    const float sfac = (float)sc[1];
    asm volatile("s_waitcnt vmcnt(0)" ::: "memory");

    // read bases (verified swizzle: phys slot = sl ^ (li&3) ^ ((li>>2)&3))
    const int pA = (sl ^ (lane & 3) ^ ((lane >> 2) & 3)) & 3;
    const char* aR0 = (const char*)lds + ((wr * 128 + li) << 6) + (pA << 4);
    const char* bR0 = (const char*)lds + 16384 + ((wc * 64 + li) << 6) + (pA << 4);
    const char* aR1 = aR0 + 24576;
    const char* bR1 = bR0 + 24576;

    // staging (verified inverse-swizzle source): chunk = 16 rows x 64 B
    const int lslot = (lane & 3) ^ ((lane >> 2) & 3) ^ ((lane >> 4) & 3);
    char* dA = (char*)lds + wid * 4096;            // A chunks wid*4..+3
    char* dB = (char*)lds + 16384 + wid * 2048;    // B chunks wid*2..+1
    const int rsub = lane >> 2;                    // 0..15
    const char* pA0 = (const char*)(Ab + (size_t)((wid * 4 + 0) * 16 + rsub) * KD + lslot * 8);
    const char* pA1 = (const char*)(Ab + (size_t)((wid * 4 + 1) * 16 + rsub) * KD + lslot * 8);
    const char* pA2 = (const char*)(Ab + (size_t)((wid * 4 + 2) * 16 + rsub) * KD + lslot * 8);
    const char* pA3 = (const char*)(Ab + (size_t)((wid * 4 + 3) * 16 + rsub) * KD + lslot * 8);
    const char* pB0 = (const char*)(Bb + (size_t)((wid * 2 + 0) * 16 + rsub) * KD + lslot * 8);
    const char* pB1 = (const char*)(Bb + (size_t)((wid * 2 + 1) * 16 + rsub) * KD + lslot * 8);

    f32x4 acc[8][4];
#pragma unroll
    for (int m = 0; m < 8; ++m)
#pragma unroll
        for (int n = 0; n < 4; ++n) acc[m][n] = (f32x4){0.f, 0.f, 0.f, 0.f};

    f16x8 af[8], bf[4];

    // prologue: stage tile 0 -> buf0
    STG6(0);
    VM0(); BARR();

    // bodies t = 0..61 (31 pairs), 62, then tail 63
#pragma unroll 1
    for (int j = 0; j < 31; ++j) {
        BODY(aR0, bR0, 24576);   // even t: read buf0, stage buf1
        BODY(aR1, bR1, 0);       // odd t:  read buf1, stage buf0
    }
    BODY(aR0, bR0, 24576);       // t=62 (stages tile 63 -> buf1)
    // t=63 tail: read buf1, no stage
    RD12(aR1, bR1);
    LGKM0();
    MM32();

    // ---- epilogue: scale by 1/scale, f32 store (verified 16x16 layout) ----
#pragma unroll
    for (int m = 0; m < 8; ++m)
#pragma unroll
        for (int n = 0; n < 4; ++n)
#pragma unroll
            for (int r4 = 0; r4 < 4; ++r4) {
                const int row = wr * 128 + m * 16 + sl * 4 + r4;
                const int col = wc * 64 + n * 16 + li;
                Cb[(size_t)row * ND + col] = acc[m][n][r4] * sfac;
            }
}

// ---------------- fallback (only if ws too small): f32 tiled, on-the-fly quant ----------------
__global__ void k_fallback(const float* __restrict__ x, const float* __restrict__ w,
                           const double* __restrict__ sc, float* __restrict__ out) {
    const int row0 = blockIdx.x * 16;
    const int col0 = blockIdx.y * 16;
    const int e = row0 / TT;
    __shared__ float xs[16][17];
    __shared__ float wq[16][17];
    const double scale = sc[0];
    const float s = (float)sc[1];
    const int tx = threadIdx.x, ty = threadIdx.y;
    const float* wbase = w + ((size_t)e * ND + col0) * KD;
    float acc = 0.f;
    for (int k0 = 0; k0 < KD; k0 += 16) {
        xs[ty][tx] = x[(size_t)(row0 + ty) * KD + k0 + tx];
        const float wv = wbase[(size_t)ty * KD + k0 + tx];
        wq[ty][tx] = (float)fmin(fmax(rint((double)wv * scale), -1.0), 1.0);
        __syncthreads();
#pragma unroll
        for (int kk = 0; kk < 16; ++kk) acc += xs[ty][kk] * wq[tx][kk];
        __syncthreads();
    }
    out[(size_t)(row0 + ty) * ND + col0 + tx] = acc * s;
}

// ---------------- launch ----------------
extern "C" void kernel_launch(void* const* d_in, const int* in_sizes, int n_in,
                              void* d_out, int out_size, void* d_ws, size_t ws_size,
                              hipStream_t stream) {
    const float* x = (const float*)d_in[0];
    const float* w = (const float*)d_in[1];
    float* out = (float*)d_out;

    double* part = (double*)d_ws;                       // 2048 * 8 B
    double* sc   = (double*)((char*)d_ws + 16384);      // [0]=scale, [1]=1/scale

    const size_t need = 65536 + NX * 2 + NW * 2;        // ~320 MiB

    hipLaunchKernelGGL(k_abs_partial, dim3(2048), dim3(256), 0, stream, w, part);
    hipLaunchKernelGGL(k_finalize,   dim3(1),    dim3(256), 0, stream, part, sc);

    if (ws_size >= need) {
        f16* xh = (f16*)((char*)d_ws + 65536);
        f16* qh = (f16*)((char*)d_ws + 65536 + NX * 2);
        hipLaunchKernelGGL(k_quant, dim3(2048), dim3(256), 0, stream, w, sc, qh);
        hipLaunchKernelGGL(k_xconv, dim3(2048), dim3(256), 0, stream, x, xh);
        hipLaunchKernelGGL(k_gemm,  dim3(NE * (TT / 256) * (ND / 128)), dim3(256), 0, stream,
                           xh, qh, sc, out);
    } else {
        dim3 grid(MT / 16, ND / 16);
        hipLaunchKernelGGL(k_fallback, grid, dim3(16, 16), 0, stream, x, w, sc, out);
    }
}

// Round 12
// 650.625 us; speedup vs baseline: 1.5457x; 1.5199x over previous
//
#include <hip/hip_runtime.h>

// Problem constants (fixed by reference)
#define NE 8
#define TT 2048            // tokens per expert
#define KD 2048            // INPUT_SIZE  (K)
#define ND 8192            // OUTPUT_SIZE (N)
#define MT (NE * TT)       // 16384 total rows
#define NW ((size_t)NE * ND * KD)   // 134217728 weight elems
#define NX ((size_t)MT * KD)        // 33554432 input elems

typedef int   i32x4 __attribute__((ext_vector_type(4)));
typedef float f32x4 __attribute__((ext_vector_type(4)));

// ---------------- K1: partial abs-sum (f64, deterministic) ----------------
__global__ void k_abs_partial(const float* __restrict__ w, double* __restrict__ part) {
    __shared__ double sred[256];
    const size_t n4 = NW / 4;
    const size_t stride = (size_t)gridDim.x * blockDim.x;
    double acc = 0.0;
    for (size_t i = (size_t)blockIdx.x * blockDim.x + threadIdx.x; i < n4; i += stride) {
        float4 v = ((const float4*)w)[i];
        acc += (double)fabsf(v.x) + (double)fabsf(v.y) + (double)fabsf(v.z) + (double)fabsf(v.w);
    }
    sred[threadIdx.x] = acc;
    __syncthreads();
    for (int s = 128; s > 0; s >>= 1) {
        if ((int)threadIdx.x < s) sred[threadIdx.x] += sred[threadIdx.x + s];
        __syncthreads();
    }
    if (threadIdx.x == 0) part[blockIdx.x] = sred[0];
}

// ---------------- K2: finalize scale ----------------
__global__ void k_finalize(const double* __restrict__ part, double* __restrict__ sc) {
    __shared__ double sred[256];
    double a = 0.0;
    for (int i = threadIdx.x; i < 2048; i += 256) a += part[i];
    sred[threadIdx.x] = a;
    __syncthreads();
    for (int s = 128; s > 0; s >>= 1) {
        if ((int)threadIdx.x < s) sred[threadIdx.x] += sred[threadIdx.x + s];
        __syncthreads();
    }
    if (threadIdx.x == 0) {
        double mean = sred[0] / (double)NW;
        double denom = mean > 1e-5 ? mean : 1e-5;
        sc[0] = 1.0 / denom;   // scale
        sc[1] = denom;         // 1/scale (output multiplier)
    }
}

// ---------------- K3: quantize w -> ternary i8 ----------------
__global__ void k_quant(const float* __restrict__ w, const double* __restrict__ sc,
                        signed char* __restrict__ q) {
    const double scale = sc[0];
    const size_t n4 = NW / 4;
    const size_t stride = (size_t)gridDim.x * blockDim.x;
    for (size_t i = (size_t)blockIdx.x * blockDim.x + threadIdx.x; i < n4; i += stride) {
        float4 v = ((const float4*)w)[i];
        const int a = (int)fmin(fmax(rint((double)v.x * scale), -1.0), 1.0);
        const int b = (int)fmin(fmax(rint((double)v.y * scale), -1.0), 1.0);
        const int c = (int)fmin(fmax(rint((double)v.z * scale), -1.0), 1.0);
        const int d = (int)fmin(fmax(rint((double)v.w * scale), -1.0), 1.0);
        ((int*)q)[i] = (a & 0xff) | ((b & 0xff) << 8) | ((c & 0xff) << 16) | (d << 24);
    }
}

// ---------------- K4: x -> per-row i8 (scale = rowmax/127) ----------------
__global__ void k_xq(const float* __restrict__ x, signed char* __restrict__ xq,
                     float* __restrict__ rscale) {
    const int lane = (int)threadIdx.x & 63;
    const int w    = (int)threadIdx.x >> 6;
    const int row  = blockIdx.x * 4 + w;          // one wave per token row
    const float* xr = x + (size_t)row * KD;
    float4 v[8];
    float mx = 0.f;
#pragma unroll
    for (int j = 0; j < 8; ++j) {
        v[j] = ((const float4*)xr)[lane + 64 * j];
        mx = fmaxf(mx, fmaxf(fmaxf(fabsf(v[j].x), fabsf(v[j].y)),
                             fmaxf(fabsf(v[j].z), fabsf(v[j].w))));
    }
#pragma unroll
    for (int s = 32; s > 0; s >>= 1) mx = fmaxf(mx, __shfl_xor(mx, s));
    const float mxs = fmaxf(mx, 1e-20f);
    if (lane == 0) rscale[row] = mxs / 127.f;
    const float inv = 127.f / mxs;
    int* o = (int*)(xq + (size_t)row * KD);
#pragma unroll
    for (int j = 0; j < 8; ++j) {
        const int a = (int)rintf(v[j].x * inv);
        const int b = (int)rintf(v[j].y * inv);
        const int c = (int)rintf(v[j].z * inv);
        const int d = (int)rintf(v[j].w * inv);
        o[lane + 64 * j] = (a & 0xff) | ((b & 0xff) << 8) | ((c & 0xff) << 16) | (d << 24);
    }
}

// ---------------- K5: grouped GEMM, 256x256x64, i8 MFMA (i32 exact) --------
// Round-6 verified skeleton, i8 data: 64-B rows (BK=64 x 1B), 4 x 16-B slots,
// SAME swizzle involution phys_slot = sl ^ (li&3) ^ ((li>>2)&3) and SAME
// inverse-swizzled staging (byte-level identical to verified f16 rounds).
// mfma_i32_16x16x64_i8: one MFMA covers K=64 -> 32 MFMA/wave/tile.
// Ring-3 LDS bufs x [A 16K | B 16K] = 96 KiB; stage tile t+2 during tile t;
// counted VM(4) once per tile (keeps t+2's 4 loads in flight, lands t+1).
// 2 phases/tile: P0 {RD A[mh0](4)+B(4) | stage A(t+2) | bar lgkm0 16 MFMA bar}
//                P1 {RD A[mh1](4)      | stage B(t+2) | bar lgkm0 16 MFMA
//                    VM(4) bar}
// Race-free: stage into buf[(t+2)%3] issues after tile t-1's reads retired
// (lgkm0 pre-barrier, 2 barriers earlier). gload imm stays 0 ALWAYS.

__device__ __forceinline__ void gload16(const void* g, void* l) {
    __builtin_amdgcn_global_load_lds(
        (const __attribute__((address_space(1))) unsigned int*)g,
        (__attribute__((address_space(3))) unsigned int*)l, 16, 0, 0);
}

#define BARR() asm volatile("s_barrier" ::: "memory")
#define SCHED0() __builtin_amdgcn_sched_barrier(0)
#define LGKM0() do { asm volatile("s_waitcnt lgkmcnt(0)" ::: "memory"); SCHED0(); } while (0)
#define VM(N) asm volatile("s_waitcnt vmcnt(" #N ")" ::: "memory")

#define RD_A(AR, MH) { _Pragma("unroll") for (int i_ = 0; i_ < 4; ++i_) \
    af[i_] = *(const i32x4*)((AR) + ((MH) * 4096 + i_ * 1024)); }
#define RD_B(BR) { _Pragma("unroll") for (int n_ = 0; n_ < 4; ++n_) \
    bf[n_] = *(const i32x4*)((BR) + n_ * 1024); }

#define STG_A(SB) do { \
    gload16(pA0, dstc + (SB)); \
    gload16(pA1, dstc + (SB) + 1024); \
    pA0 += 64; pA1 += 64; \
    asm volatile("" : "+v"(pA0), "+v"(pA1)); } while (0)
#define STG_B(SB) do { \
    gload16(pB0, dstc + (SB) + 16384); \
    gload16(pB1, dstc + (SB) + 17408); \
    pB0 += 64; pB1 += 64; \
    asm volatile("" : "+v"(pB0), "+v"(pB1)); } while (0)

#define MMQ(MB) do { \
  __builtin_amdgcn_s_setprio(1); \
  _Pragma("unroll") for (int m_ = 0; m_ < 4; ++m_) \
    _Pragma("unroll") for (int n_ = 0; n_ < 4; ++n_) \
      acc[(MB) + m_][n_] = __builtin_amdgcn_mfma_i32_16x16x64_i8( \
          af[m_], bf[n_], acc[(MB) + m_][n_], 0, 0, 0); \
  __builtin_amdgcn_s_setprio(0); } while (0)

// one K-tile: read (AR,BR) = buf[t%3], stage tile t+2 into SB = buf[(t+2)%3]
#define TILE_S(AR, BR, SB) do { \
    RD_A(AR, 0); RD_B(BR); \
    STG_A(SB); \
    BARR(); LGKM0(); MMQ(0); BARR(); \
    RD_A(AR, 1); \
    STG_B(SB); \
    BARR(); LGKM0(); MMQ(4); VM(4); BARR(); \
} while (0)

#define TILE_30(AR, BR) do { \
    RD_A(AR, 0); RD_B(BR); \
    BARR(); LGKM0(); MMQ(0); BARR(); \
    RD_A(AR, 1); \
    BARR(); LGKM0(); MMQ(4); VM(0); BARR(); \
} while (0)

#define TILE_31(AR, BR) do { \
    RD_A(AR, 0); RD_B(BR); \
    BARR(); LGKM0(); MMQ(0); BARR(); \
    RD_A(AR, 1); \
    LGKM0(); MMQ(4); \
} while (0)

__global__ __launch_bounds__(512, 2)
void k_gemm(const signed char* __restrict__ xq, const signed char* __restrict__ wq,
            const double* __restrict__ sc, const float* __restrict__ rscale,
            float* __restrict__ out) {
    __shared__ char lds[3 * 32768];   // ring-3, 96 KiB

    const int lane = (int)threadIdx.x & 63;
    const int wid  = (int)threadIdx.x >> 6;   // 0..7
    const int wr   = wid >> 2;                 // 0..1  (M strip of 128)
    const int wc   = wid & 3;                  // 0..3  (N strip of 64)
    const int li   = lane & 15;
    const int sl   = lane >> 4;                // k-slot 0..3 (16 B each)

    // XCD-aware swizzle + round-6 block mapping (FETCH ~compulsory proven)
    const int wg = ((int)blockIdx.x & 7) * 256 + ((int)blockIdx.x >> 3);
    const int e  = wg >> 8;
    const int u  = wg & 255;
    const int mt = (u >> 1) & 7;
    const int nt = (((u >> 4) << 1) | (u & 1));

    const signed char* Ab = xq + ((size_t)e * TT + (size_t)mt * 256) * KD;
    const signed char* Bb = wq + ((size_t)e * ND + (size_t)nt * 256) * KD;
    float*             Cb = out + ((size_t)e * TT + (size_t)mt * 256) * ND + (size_t)nt * 256;

    const float sfac = (float)sc[1];
    const float* rsc = rscale + (size_t)e * TT + (size_t)mt * 256 + wr * 128;
    asm volatile("s_waitcnt vmcnt(0)" ::: "memory");

    // read bases (verified swizzle: phys slot = sl ^ (li&3) ^ ((li>>2)&3))
    const int pA = (sl ^ (lane & 3) ^ ((lane >> 2) & 3)) & 3;
    const char* aR0 = (const char*)lds + ((wr * 128 + li) << 6) + (pA << 4);
    const char* bR0 = (const char*)lds + 16384 + ((wc * 64 + li) << 6) + (pA << 4);
    const char* aR1 = aR0 + 32768;
    const char* bR1 = bR0 + 32768;
    const char* aR2 = aR0 + 65536;
    const char* bR2 = bR0 + 65536;

    // staging (verified inverse-swizzle source): chunk = 16 rows x 64 B
    const int lslot = (lane & 3) ^ ((lane >> 2) & 3) ^ ((lane >> 4) & 3);
    char* dstc = (char*)lds + wid * 2048;
    const int srow0 = (wid * 2 + 0) * 16 + (lane >> 2);   // 0..255
    const int srow1 = (wid * 2 + 1) * 16 + (lane >> 2);
    const char* pA0 = (const char*)(Ab + (size_t)srow0 * KD + lslot * 16);
    const char* pA1 = (const char*)(Ab + (size_t)srow1 * KD + lslot * 16);
    const char* pB0 = (const char*)(Bb + (size_t)srow0 * KD + lslot * 16);
    const char* pB1 = (const char*)(Bb + (size_t)srow1 * KD + lslot * 16);

    i32x4 acc[8][4];
#pragma unroll
    for (int m = 0; m < 8; ++m)
#pragma unroll
        for (int n = 0; n < 4; ++n) acc[m][n] = (i32x4){0, 0, 0, 0};

    i32x4 af[4], bf[4];

    // prologue: stage tiles 0,1 -> buf0,buf1; wait tile 0
    STG_A(0);     STG_B(0);
    STG_A(32768); STG_B(32768);
    VM(4);
    BARR();

    // tiles 0..29 (3 per iteration; stages tiles 2..31)
#pragma unroll 1
    for (int j = 0; j < 10; ++j) {
        TILE_S(aR0, bR0, 65536);   // t%3==0: read buf0, stage buf2
        TILE_S(aR1, bR1, 0);       // t%3==1: read buf1, stage buf0
        TILE_S(aR2, bR2, 32768);   // t%3==2: read buf2, stage buf1
    }
    TILE_30(aR0, bR0);             // tile 30 (buf0), drain tile 31
    TILE_31(aR1, bR1);             // tile 31 (buf1)

    // ---- epilogue: out = acc_i32 * s * rowscale, f32 store ----
#pragma unroll
    for (int m = 0; m < 8; ++m) {
        float fac[4];
#pragma unroll
        for (int r4 = 0; r4 < 4; ++r4)
            fac[r4] = sfac * rsc[m * 16 + sl * 4 + r4];
#pragma unroll
        for (int n = 0; n < 4; ++n)
#pragma unroll
            for (int r4 = 0; r4 < 4; ++r4) {
                const int row = wr * 128 + m * 16 + sl * 4 + r4;
                const int col = wc * 64 + n * 16 + li;
                Cb[(size_t)row * ND + col] = (float)acc[m][n][r4] * fac[r4];
            }
    }
}

// ---------------- fallback (only if ws too small): f32 tiled, on-the-fly quant ----------------
__global__ void k_fallback(const float* __restrict__ x, const float* __restrict__ w,
                           const double* __restrict__ sc, float* __restrict__ out) {
    const int row0 = blockIdx.x * 16;
    const int col0 = blockIdx.y * 16;
    const int e = row0 / TT;
    __shared__ float xs[16][17];
    __shared__ float wq[16][17];
    const double scale = sc[0];
    const float s = (float)sc[1];
    const int tx = threadIdx.x, ty = threadIdx.y;
    const float* wbase = w + ((size_t)e * ND + col0) * KD;
    float acc = 0.f;
    for (int k0 = 0; k0 < KD; k0 += 16) {
        xs[ty][tx] = x[(size_t)(row0 + ty) * KD + k0 + tx];
        const float wv = wbase[(size_t)ty * KD + k0 + tx];
        wq[ty][tx] = (float)fmin(fmax(rint((double)wv * scale), -1.0), 1.0);
        __syncthreads();
#pragma unroll
        for (int kk = 0; kk < 16; ++kk) acc += xs[ty][kk] * wq[tx][kk];
        __syncthreads();
    }
    out[(size_t)(row0 + ty) * ND + col0 + tx] = acc * s;
}

// ---------------- launch ----------------
extern "C" void kernel_launch(void* const* d_in, const int* in_sizes, int n_in,
                              void* d_out, int out_size, void* d_ws, size_t ws_size,
                              hipStream_t stream) {
    const float* x = (const float*)d_in[0];
    const float* w = (const float*)d_in[1];
    float* out = (float*)d_out;

    double* part   = (double*)d_ws;                        // 16 KiB
    double* sc     = (double*)((char*)d_ws + 16384);       // scale, 1/scale
    float*  rscale = (float*)((char*)d_ws + 32768);        // 64 KiB (16384 rows)
    signed char* xq = (signed char*)((char*)d_ws + 98304); // NX bytes
    signed char* wq = xq + NX;                             // NW bytes

    const size_t need = 98304 + NX + NW;                   // ~160 MiB

    hipLaunchKernelGGL(k_abs_partial, dim3(2048), dim3(256), 0, stream, w, part);
    hipLaunchKernelGGL(k_finalize,   dim3(1),    dim3(256), 0, stream, part, sc);

    if (ws_size >= need) {
        hipLaunchKernelGGL(k_quant, dim3(2048), dim3(256), 0, stream, w, sc, wq);
        hipLaunchKernelGGL(k_xq,    dim3(MT / 4), dim3(256), 0, stream, x, xq, rscale);
        hipLaunchKernelGGL(k_gemm,  dim3(NE * (TT / 256) * (ND / 256)), dim3(512), 0, stream,
                           xq, wq, sc, rscale, out);
    } else {
        dim3 grid(MT / 16, ND / 16);
        hipLaunchKernelGGL(k_fallback, grid, dim3(16, 16), 0, stream, x, w, sc, out);
    }
}